// Round 4
// baseline (376.611 us; speedup 1.0000x reference)
//
#include <hip/hip_runtime.h>

typedef __attribute__((ext_vector_type(8))) short bf16x8;
typedef __attribute__((ext_vector_type(4))) float f32x4;
typedef __attribute__((ext_vector_type(2))) unsigned int u32x2;

#define MFMA16(a, b, c) __builtin_amdgcn_mfma_f32_16x16x32_bf16((a), (b), (c), 0, 0, 0)

__device__ __forceinline__ short f2bf(float f) {
    union { float f; unsigned u; } v; v.f = f;
    return (short)((v.u + 0x7FFFu + ((v.u >> 16) & 1u)) >> 16);  // RNE
}

#if defined(__has_builtin)
#if __has_builtin(__builtin_amdgcn_cvt_pk_bf16_f32)
#define HAVE_PKCVT 1
#endif
#endif

__device__ __forceinline__ unsigned pk2(float a, float b) {
#ifdef HAVE_PKCVT
    auto v = __builtin_amdgcn_cvt_pk_bf16_f32(a, b);
    union { decltype(v) x; unsigned u; } c; c.x = v; return c.u;
#else
    return (unsigned)(unsigned short)f2bf(a) | ((unsigned)(unsigned short)f2bf(b) << 16);
#endif
}

__device__ __forceinline__ float frcp(float x) {
#if defined(__has_builtin) && __has_builtin(__builtin_amdgcn_rcpf)
    return __builtin_amdgcn_rcpf(x);
#else
    return 1.0f / x;
#endif
}

__device__ __forceinline__ f32x4 fzero4() { f32x4 z; z[0]=0.f; z[1]=0.f; z[2]=0.f; z[3]=0.f; return z; }

// ws (shorts): [0,196608) wqkv bf16 [768][256]; [196608,262144) wproj bf16 [256][256]
__global__ __launch_bounds__(256, 1)
void convw_kernel(const float* __restrict__ wqkv, const float* __restrict__ wproj,
                  short* __restrict__ wsb)
{
    int i = (blockIdx.x * 256 + threadIdx.x) * 8;
    const float* src = (i < 196608) ? (wqkv + i) : (wproj + (i - 196608));
    f32x4 v0 = *(const f32x4*)(src);
    f32x4 v1 = *(const f32x4*)(src + 4);
    u32x2 p0, p1;
    p0[0] = pk2(v0[0], v0[1]); p0[1] = pk2(v0[2], v0[3]);
    p1[0] = pk2(v1[0], v1[1]); p1[1] = pk2(v1[2], v1[3]);
    *(u32x2*)(wsb + i)     = p0;
    *(u32x2*)(wsb + i + 4) = p1;
}

// LDS (shorts): XA [64][264] = 16896 @0  (X bf16 -> attn_out bf16)
//               SW per-wave 2560 shorts @16896 + w*2560  ([64][40] Q/K/P or [32][72] V^T)
// total = 54272 B -> 3 blocks/CU (160 KB / 54272 = 3.01)
#define SMEM_BYTES 54272

__global__ __launch_bounds__(256, 3)
void ga2d_kernel(const float* __restrict__ x,
                 const short* __restrict__ wsb,
                 const float* __restrict__ bqkv,
                 const float* __restrict__ bproj,
                 float* __restrict__ out)
{
    extern __shared__ short smem[];
    short* XA = smem;                                   // [64][264]
    const int tid  = threadIdx.x;
    const int w    = tid >> 6;
    const int lane = tid & 63;
    const int l16  = lane & 15;
    const int q4   = lane >> 4;
    short* SW = smem + 16896 + w * 2560;                // per-wave scratch

    const int blk = blockIdx.x;                         // (b, hp, wp)
    const int bb  = blk >> 6;
    const int hp  = (blk >> 3) & 7;
    const int wp  = blk & 7;
    const size_t gbase = (size_t)bb * 64 * 64 * 256;

    // ---------------- phase 0: gather X (f32) -> bf16 LDS ----------------
    #pragma unroll
    for (int i = 0; i < 16; ++i) {
        int id  = i * 256 + tid;
        int tok = id >> 6, c4 = id & 63;
        int hr  = (tok >> 3) * 8 + hp;
        int wc  = (tok & 7) * 8 + wp;
        f32x4 v = *(const f32x4*)(x + gbase + ((size_t)hr * 64 + wc) * 256 + c4 * 4);
        u32x2 p; p[0] = pk2(v[0], v[1]); p[1] = pk2(v[2], v[3]);
        *(u32x2*)(XA + tok * 264 + c4 * 4) = p;
    }
    __syncthreads();

    // ---------------- phase 1: QKV as six N=32 panels (head-aligned) ----------------
    bf16x8 qa[2][4], kb[2][4], vb[2][2][2];
    #pragma unroll
    for (int hl = 0; hl < 2; ++hl) {
        #pragma unroll
        for (int g3 = 0; g3 < 3; ++g3) {                // 0:Q 1:K 2:V
            const int colbase = g3 * 256 + w * 64 + hl * 32;
            const short* WB = wsb + (size_t)colbase * 256;
            f32x4 acc[2][4];
            #pragma unroll
            for (int n = 0; n < 2; ++n) {
                const float bi = bqkv[colbase + n * 16 + l16];
                #pragma unroll
                for (int m = 0; m < 4; ++m) {
                    acc[n][m][0] = bi; acc[n][m][1] = bi; acc[n][m][2] = bi; acc[n][m][3] = bi;
                }
            }
            #pragma unroll
            for (int k = 0; k < 8; ++k) {
                const int koff = k * 32 + q4 * 8;
                bf16x8 a[4], bw[2];
                #pragma unroll
                for (int m = 0; m < 4; ++m)
                    a[m] = *(const bf16x8*)(XA + (m * 16 + l16) * 264 + koff);
                #pragma unroll
                for (int n = 0; n < 2; ++n)
                    bw[n] = *(const bf16x8*)(WB + (size_t)(n * 16 + l16) * 256 + koff);
                #pragma unroll
                for (int n = 0; n < 2; ++n)
                    #pragma unroll
                    for (int m = 0; m < 4; ++m)
                        acc[n][m] = MFMA16(a[m], bw[n], acc[n][m]);
            }
            if (g3 < 2) {                               // Q,K: [token][dim32] stride 40
                #pragma unroll
                for (int n = 0; n < 2; ++n)
                    #pragma unroll
                    for (int m = 0; m < 4; ++m)
                        #pragma unroll
                        for (int r = 0; r < 4; ++r)
                            SW[(m * 16 + q4 * 4 + r) * 40 + n * 16 + l16] = f2bf(acc[n][m][r]);
                if (g3 == 0) {
                    #pragma unroll
                    for (int m = 0; m < 4; ++m)
                        qa[hl][m] = *(const bf16x8*)(SW + (m * 16 + l16) * 40 + q4 * 8);
                } else {
                    #pragma unroll
                    for (int n = 0; n < 4; ++n)
                        kb[hl][n] = *(const bf16x8*)(SW + (n * 16 + l16) * 40 + q4 * 8);
                }
            } else {                                    // V: transposed [dim32][token64+pad] stride 72
                #pragma unroll
                for (int n = 0; n < 2; ++n)
                    #pragma unroll
                    for (int m = 0; m < 4; ++m) {
                        u32x2 p;
                        p[0] = pk2(acc[n][m][0], acc[n][m][1]);
                        p[1] = pk2(acc[n][m][2], acc[n][m][3]);
                        *(u32x2*)(SW + (n * 16 + l16) * 72 + m * 16 + q4 * 4) = p;
                    }
                #pragma unroll
                for (int dt = 0; dt < 2; ++dt)
                    #pragma unroll
                    for (int kt = 0; kt < 2; ++kt)
                        vb[hl][dt][kt] = *(const bf16x8*)(SW + (dt * 16 + l16) * 72 + kt * 32 + q4 * 8);
            }
        }
    }

    // ---------------- phase 2: attention, wave-local; barrier before first XA overwrite ----
    const float kscl = 0.25503546f;                     // log2(e) / sqrt(32)
    #pragma unroll
    for (int hl = 0; hl < 2; ++hl) {
        f32x4 s[4][4];
        #pragma unroll
        for (int m = 0; m < 4; ++m)
            #pragma unroll
            for (int n = 0; n < 4; ++n)
                s[m][n] = MFMA16(qa[hl][m], kb[hl][n], fzero4());

        float rinv[4][4];
        #pragma unroll
        for (int m = 0; m < 4; ++m) {
            #pragma unroll
            for (int r = 0; r < 4; ++r) {
                float t = 0.f;
                #pragma unroll
                for (int n = 0; n < 4; ++n) {
                    float p = exp2f(s[m][n][r] * kscl);   // no max-sub: |s*scale| << 88
                    s[m][n][r] = p;
                    t += p;
                }
                t += __shfl_xor(t, 1);
                t += __shfl_xor(t, 2);
                t += __shfl_xor(t, 4);
                t += __shfl_xor(t, 8);
                rinv[m][r] = frcp(t);
            }
        }

        f32x4 o[4][2];
        #pragma unroll
        for (int m = 0; m < 4; ++m) { o[m][0] = fzero4(); o[m][1] = fzero4(); }
        #pragma unroll
        for (int kt = 0; kt < 2; ++kt) {                // P in two 32-key halves through scratch
            #pragma unroll
            for (int nl = 0; nl < 2; ++nl)
                #pragma unroll
                for (int m = 0; m < 4; ++m)
                    #pragma unroll
                    for (int r = 0; r < 4; ++r)
                        SW[(m * 16 + q4 * 4 + r) * 40 + nl * 16 + l16] = f2bf(s[m][2 * kt + nl][r]);
            bf16x8 pa[4];
            #pragma unroll
            for (int m = 0; m < 4; ++m)
                pa[m] = *(const bf16x8*)(SW + (m * 16 + l16) * 40 + q4 * 8);
            #pragma unroll
            for (int m = 0; m < 4; ++m)
                #pragma unroll
                for (int dt = 0; dt < 2; ++dt)
                    o[m][dt] = MFMA16(pa[m], vb[hl][dt][kt], o[m][dt]);
        }

        if (hl == 0) __syncthreads();   // all waves done reading X; XA now writable

        #pragma unroll
        for (int m = 0; m < 4; ++m)
            #pragma unroll
            for (int dt = 0; dt < 2; ++dt)
                #pragma unroll
                for (int r = 0; r < 4; ++r)
                    XA[(m * 16 + q4 * 4 + r) * 264 + w * 64 + hl * 32 + dt * 16 + l16] =
                        f2bf(o[m][dt][r] * rinv[m][r]);
    }
    __syncthreads();

    // ---------------- phase 3: out projection (M=64,N=64/wave,K=256) ----------------
    {
        const short* WPb = wsb + 196608 + (size_t)(w * 64) * 256;
        f32x4 pc[4][4];
        #pragma unroll
        for (int n = 0; n < 4; ++n) {
            const float bi = bproj[w * 64 + n * 16 + l16];
            #pragma unroll
            for (int m = 0; m < 4; ++m) {
                pc[n][m][0] = bi; pc[n][m][1] = bi; pc[n][m][2] = bi; pc[n][m][3] = bi;
            }
        }
        #pragma unroll
        for (int k = 0; k < 8; ++k) {
            const int koff = k * 32 + q4 * 8;
            bf16x8 a[4], bw[4];
            #pragma unroll
            for (int m = 0; m < 4; ++m)
                a[m] = *(const bf16x8*)(XA + (m * 16 + l16) * 264 + koff);
            #pragma unroll
            for (int n = 0; n < 4; ++n)
                bw[n] = *(const bf16x8*)(WPb + (size_t)(n * 16 + l16) * 256 + koff);
            #pragma unroll
            for (int n = 0; n < 4; ++n)
                #pragma unroll
                for (int m = 0; m < 4; ++m)
                    pc[n][m] = MFMA16(a[m], bw[n], pc[n][m]);
        }
        #pragma unroll
        for (int n = 0; n < 4; ++n) {
            const int col = w * 64 + n * 16 + l16;
            #pragma unroll
            for (int m = 0; m < 4; ++m) {
                #pragma unroll
                for (int r = 0; r < 4; ++r) {
                    const int tok = m * 16 + q4 * 4 + r;
                    const int hr  = (tok >> 3) * 8 + hp;
                    const int wc  = (tok & 7) * 8 + wp;
                    out[gbase + ((size_t)hr * 64 + wc) * 256 + col] = pc[n][m][r];
                }
            }
        }
    }
}

extern "C" void kernel_launch(void* const* d_in, const int* in_sizes, int n_in,
                              void* d_out, int out_size, void* d_ws, size_t ws_size,
                              hipStream_t stream) {
    const float* x     = (const float*)d_in[0];
    const float* wqkv  = (const float*)d_in[1];
    const float* bqkv  = (const float*)d_in[2];
    const float* wproj = (const float*)d_in[3];
    const float* bproj = (const float*)d_in[4];
    float*       out   = (float*)d_out;
    short*       wsb   = (short*)d_ws;       // 512 KB bf16 weights

    convw_kernel<<<128, 256, 0, stream>>>(wqkv, wproj, wsb);

    hipFuncSetAttribute(reinterpret_cast<const void*>(ga2d_kernel),
                        hipFuncAttributeMaxDynamicSharedMemorySize, SMEM_BYTES);
    ga2d_kernel<<<2048, 256, SMEM_BYTES, stream>>>(x, wsb, bqkv, bproj, out);
}